// Round 7
// baseline (820.389 us; speedup 1.0000x reference)
//
#include <hip/hip_runtime.h>
#include <stdint.h>

typedef __bf16   bf16x8  __attribute__((ext_vector_type(8)));
typedef float    f32x4   __attribute__((ext_vector_type(4)));
typedef uint16_t u16x8   __attribute__((ext_vector_type(8)));

using as1_cvp = const __attribute__((address_space(1))) void*;
using as3_vp  = __attribute__((address_space(3))) void*;

__device__ __forceinline__ uint16_t f2bf(float f) {
    uint32_t u = __float_as_uint(f);
    u += 0x7FFF + ((u >> 16) & 1);          // RNE
    return (uint16_t)(u >> 16);
}

__device__ __forceinline__ void gload16(const void* g, void* l) {
    __builtin_amdgcn_global_load_lds((as1_cvp)g, (as3_vp)l, 16, 0, 0);
}

#define MFMA16(a, b, c) __builtin_amdgcn_mfma_f32_16x16x32_bf16((a), (b), (c), 0, 0, 0)

// ---------------------------------------------------------------- f32 -> bf16
__global__ __launch_bounds__(256)
void cvt_bf16(const float* __restrict__ in, uint16_t* __restrict__ out, int n8)
{
    int i = blockIdx.x * 256 + threadIdx.x;
    if (i >= n8) return;
    const float4* p = reinterpret_cast<const float4*>(in) + (size_t)i * 2;
    float4 a = p[0], b = p[1];
    u16x8 o;
    o[0] = f2bf(a.x); o[1] = f2bf(a.y); o[2] = f2bf(a.z); o[3] = f2bf(a.w);
    o[4] = f2bf(b.x); o[5] = f2bf(b.y); o[6] = f2bf(b.z); o[7] = f2bf(b.w);
    reinterpret_cast<u16x8*>(out)[i] = o;
}

// ---------------------------------------------------------------------------
// 256x256 GEMM, r6 phase structure + f32 B operand (cvt fused into staging).
// C = A * Bt^T + bias. A [M x K] bf16, Bt [N x K] FLOAT32 row-major.
// 8 waves (2M x 4N), BK=64 as two K-halves of 32 (64B LDS rows, 16B block
// ^= (row>>1)&3 -> 0 conflicts, r4). A staged via global_load_lds; B staged
// via regs: float4 loads one phase ahead -> f2bf -> ds_write_b128 to the
// SAME swizzled layout (read side identical to r6).
// vmcnt in-order counts/tile: [Ak1(t+1)2, Bf32k1(t+1)4, Ak0(t+2)2,
// Bf32k0(t+2)4]; ph1 vmcnt(6) completes {Ak0,Bf32k0}(t+1); ph3 vmcnt(6)
// completes {Ak1,Bf32k1}(t+1). Writes precede prefetch reads (sched_barrier
// pinned) so lgkmcnt(8)/(0) certifies them without draining prefetches.
// ---------------------------------------------------------------------------
template <int OUT_BF16>
__global__ __launch_bounds__(512, 2)
void gemm256(const uint16_t* __restrict__ A, const float* __restrict__ Bt,
             const float* __restrict__ bias, void* __restrict__ Cout,
             int M, int N, int K)
{
    __shared__ uint16_t lds[65536];        // [buf][kh] x (A 256x32 | B 256x32)
    const int NT = K >> 6;                 // K-tiles of 64

    int bid = blockIdx.x;
    bid = (bid & 7) * 32 + (bid >> 3);     // XCD-aware swizzle (nwg=256, %8==0)
    const int bx = bid & 15, by = bid >> 4;
    const int rb = by * 256, cb = bx * 256;

    const int tid  = threadIdx.x;
    const int w    = tid >> 6;
    const int lane = tid & 63;
    const int g    = lane >> 4;
    const int l16  = lane & 15;
    const int wm   = w >> 2;               // 0..1
    const int wn   = w & 3;                // 0..3
    const int srow = lane >> 2;            // stage: 4 lanes per 64B row
    const int sblk = lane & 3;             // stage: 16B block within row

    f32x4 acc[8][4] = {};

    auto stageA = [&](int buf, int kh, int kbase) {
#pragma unroll
        for (int i = 0; i < 2; ++i) {
            const int row = i * 128 + w * 16 + srow;
            const uint16_t* src = A + (size_t)(rb + row) * K + kbase
                                    + ((sblk ^ ((row >> 1) & 3)) << 3);
            gload16(src, &lds[(buf * 2 + kh) * 16384 + i * 4096 + w * 512]);
        }
    };
    // issue 4x float4 loads for one B unit (same swizzled source pattern)
    auto loadB = [&](int kbase, float4* dst) {
#pragma unroll
        for (int i = 0; i < 2; ++i) {
            const int row = i * 128 + w * 16 + srow;
            const float* s = Bt + (size_t)(cb + row) * K + kbase
                               + ((sblk ^ ((row >> 1) & 3)) << 3);
            dst[i * 2 + 0] = *reinterpret_cast<const float4*>(s);
            dst[i * 2 + 1] = *reinterpret_cast<const float4*>(s + 4);
        }
    };
    // convert + ds_write one B unit into the linear-chunk layout (identical
    // destinations to what global_load_lds produced in r6)
    auto writeB = [&](int buf, int kh, const float4* src) {
#pragma unroll
        for (int i = 0; i < 2; ++i) {
            const float4 lo = src[i * 2], hi = src[i * 2 + 1];
            u16x8 o;
            o[0] = f2bf(lo.x); o[1] = f2bf(lo.y); o[2] = f2bf(lo.z); o[3] = f2bf(lo.w);
            o[4] = f2bf(hi.x); o[5] = f2bf(hi.y); o[6] = f2bf(hi.z); o[7] = f2bf(hi.w);
            *reinterpret_cast<u16x8*>(
                &lds[(buf * 2 + kh) * 16384 + 8192 + i * 4096 + w * 512 + lane * 8]) = o;
        }
    };

    auto readA = [&](int base, int grp, bf16x8* dst) {
#pragma unroll
        for (int mi = 0; mi < 4; ++mi) {
            const int r = wm * 128 + grp * 64 + mi * 16 + l16;
            dst[mi] = *reinterpret_cast<const bf16x8*>(
                &lds[base + r * 32 + ((g ^ ((r >> 1) & 3)) << 3)]);
        }
    };
    auto readB = [&](int base, bf16x8* dst) {
#pragma unroll
        for (int n = 0; n < 4; ++n) {
            const int c = wn * 64 + n * 16 + l16;
            dst[n] = *reinterpret_cast<const bf16x8*>(
                &lds[base + 8192 + c * 32 + ((g ^ ((c >> 1) & 3)) << 3)]);
        }
    };

    auto mfma_grp = [&](int grp, const bf16x8* af, const bf16x8* bf) {
        __builtin_amdgcn_s_setprio(1);
#pragma unroll
        for (int mi = 0; mi < 4; ++mi)
#pragma unroll
            for (int n = 0; n < 4; ++n)
                acc[grp * 4 + mi][n] = MFMA16(af[mi], bf[n], acc[grp * 4 + mi][n]);
        __builtin_amdgcn_s_setprio(0);
    };

    // ---- prologue: A t0k0, Bf32 t0k0, A t0k1, Bf32 t0k1, A t1k0, Bf32 t1k0
    float4 q0[4], q1[4], pb0[4];
    stageA(0, 0, 0);   loadB(0,  q0);
    stageA(0, 1, 32);  loadB(32, q1);
    stageA(1, 0, 64);  loadB(64, pb0);
    asm volatile("s_waitcnt vmcnt(6)" ::: "memory");   // through Bf32 t0k1
    writeB(0, 0, q0);
    writeB(0, 1, q1);
    asm volatile("s_waitcnt lgkmcnt(0)" ::: "memory");
    __builtin_amdgcn_s_barrier();

    for (int t = 0; t < NT; ++t) {
        const int cur = t & 1, nxt = cur ^ 1;
        const int b0 = (cur * 2 + 0) * 16384;
        const int b1 = (cur * 2 + 1) * 16384;
        bf16x8 af0[4], af1[4], af2[4], af3[4], bf0[4], bf1[4];
        float4 pb1[4];

        // ---- ph0: stage-issue Ak1(t+1); read af0,bf0,af1; MFMA kh0-grp0
        if (t + 1 < NT) stageA(nxt, 1, (t + 1) * 64 + 32);
        readA(b0, 0, af0); readB(b0, bf0);
        readA(b0, 1, af1);
        mfma_grp(0, af0, bf0);
        __builtin_amdgcn_sched_barrier(0);
        __builtin_amdgcn_s_barrier();

        // ---- ph1: issue Bf32k1(t+1); MFMA kh0-grp1; vmcnt -> write
        //      Bk0(t+1); then prefetch bf1,af2; lgkmcnt(8) certifies writes
        if (t + 1 < NT) loadB((t + 1) * 64 + 32, pb1);
        mfma_grp(1, af1, bf0);
        __builtin_amdgcn_sched_barrier(0);
        if (t + 1 < NT) {
            if (t + 2 < NT) asm volatile("s_waitcnt vmcnt(6)" ::: "memory");
            else            asm volatile("s_waitcnt vmcnt(0)" ::: "memory");
            writeB(nxt, 0, pb0);
        }
        __builtin_amdgcn_sched_barrier(0);
        readB(b1, bf1);
        readA(b1, 0, af2);
        asm volatile("s_waitcnt lgkmcnt(8)" ::: "memory");
        __builtin_amdgcn_s_barrier();

        // ---- ph2: stage-issue Ak0(t+2); read af3; MFMA kh1-grp0
        if (t + 2 < NT) stageA(cur, 0, (t + 2) * 64);
        readA(b1, 1, af3);
        mfma_grp(0, af2, bf1);
        __builtin_amdgcn_sched_barrier(0);
        __builtin_amdgcn_s_barrier();

        // ---- ph3: issue Bf32k0(t+2); MFMA kh1-grp1; vmcnt -> write Bk1(t+1)
        if (t + 2 < NT) loadB((t + 2) * 64, pb0);
        mfma_grp(1, af3, bf1);
        __builtin_amdgcn_sched_barrier(0);
        if (t + 1 < NT) {
            if (t + 2 < NT) asm volatile("s_waitcnt vmcnt(6)" ::: "memory");
            else            asm volatile("s_waitcnt vmcnt(0)" ::: "memory");
            writeB(nxt, 1, pb1);
            asm volatile("s_waitcnt lgkmcnt(0)" ::: "memory");
        }
        __builtin_amdgcn_s_barrier();
    }

    // ---- epilogue (16x16 C/D layout: col = l16, row = 4g + r)
    float bv[4];
#pragma unroll
    for (int n = 0; n < 4; ++n) bv[n] = bias[cb + wn * 64 + n * 16 + l16];

#pragma unroll
    for (int m = 0; m < 8; ++m) {
#pragma unroll
        for (int n = 0; n < 4; ++n) {
            const int col = cb + wn * 64 + n * 16 + l16;
#pragma unroll
            for (int r = 0; r < 4; ++r) {
                const int row = rb + wm * 128 + m * 16 + g * 4 + r;
                float v = acc[m][n][r] + bv[n];
                if (OUT_BF16)
                    ((uint16_t*)Cout)[(size_t)row * N + col] = f2bf(v);
                else
                    ((float*)Cout)[(size_t)row * N + col] = v;
            }
        }
    }
}

// ------------------------------------------------------------------ attention
// One block per (bb, hh). 4 waves; wave w owns query rows [16w, 16w+16).
// Unscaled softmax(Q K^T) V, output scattered through the reference's
// cat/transpose/view permutation directly into Y (bf16 [4096 x 4096]).
__global__ __launch_bounds__(256)
void attn_kernel(const uint16_t* __restrict__ Q, const uint16_t* __restrict__ Kg,
                 const uint16_t* __restrict__ V, uint16_t* __restrict__ Y)
{
    const int bid = blockIdx.x;
    const int hh  = bid & 63;
    const int bb  = bid >> 6;
    const int tid = threadIdx.x;
    const int w   = tid >> 6, lane = tid & 63, g = lane >> 4, l16 = lane & 15;

    __shared__ uint16_t Vt[64 * 64];   // V transposed, XOR-swizzled (8 KB)
    __shared__ uint16_t Pl[64 * 64];   // P bf16, XOR-swizzled (8 KB)

    // ---- stage V transposed: Vt[l][k] = V[k][l], swizzle elem k ^= (l&7)<<3
    {
        const int k  = tid >> 2;
        const int l0 = (tid & 3) * 16;
        const uint16_t* src = V + (size_t)(bb * 64 + k) * 4096 + hh * 64 + l0;
        u16x8 v0 = *reinterpret_cast<const u16x8*>(src);
        u16x8 v1 = *reinterpret_cast<const u16x8*>(src + 8);
#pragma unroll
        for (int i = 0; i < 8; ++i) {
            int l = l0 + i;
            Vt[l * 64 + (k ^ ((l & 7) << 3))] = v0[i];
        }
#pragma unroll
        for (int i = 0; i < 8; ++i) {
            int l = l0 + 8 + i;
            Vt[l * 64 + (k ^ ((l & 7) << 3))] = v1[i];
        }
    }

    // ---- S = Q K^T (rows 16w..16w+16, all 64 cols), direct-global fragments
    f32x4 sa[4] = {};
    {
        const uint16_t* qrow = Q + (size_t)(bb * 64 + w * 16 + l16) * 4096 + hh * 64 + g * 8;
        bf16x8 a0 = *reinterpret_cast<const bf16x8*>(qrow);
        bf16x8 a1 = *reinterpret_cast<const bf16x8*>(qrow + 32);
#pragma unroll
        for (int n = 0; n < 4; ++n) {
            const uint16_t* krow = Kg + (size_t)(bb * 64 + n * 16 + l16) * 4096 + hh * 64 + g * 8;
            bf16x8 b0 = *reinterpret_cast<const bf16x8*>(krow);
            bf16x8 b1 = *reinterpret_cast<const bf16x8*>(krow + 32);
            sa[n] = MFMA16(a0, b0, sa[n]);
            sa[n] = MFMA16(a1, b1, sa[n]);
        }
    }

    // ---- softmax (no 1/sqrt(hd) scale, faithful). Row q = 16w + 4g + j;
    // its 64 values live as regs n=0..3 across the 16-lane group (l16).
    float p[4][4];
#pragma unroll
    for (int j = 0; j < 4; ++j) {
        float mx = fmaxf(fmaxf(sa[0][j], sa[1][j]), fmaxf(sa[2][j], sa[3][j]));
        mx = fmaxf(mx, __shfl_xor(mx, 1));
        mx = fmaxf(mx, __shfl_xor(mx, 2));
        mx = fmaxf(mx, __shfl_xor(mx, 4));
        mx = fmaxf(mx, __shfl_xor(mx, 8));
        float s = 0.f;
#pragma unroll
        for (int n = 0; n < 4; ++n) { p[n][j] = __expf(sa[n][j] - mx); s += p[n][j]; }
        s += __shfl_xor(s, 1);
        s += __shfl_xor(s, 2);
        s += __shfl_xor(s, 4);
        s += __shfl_xor(s, 8);
        float inv = 1.0f / s;
#pragma unroll
        for (int n = 0; n < 4; ++n) p[n][j] *= inv;
    }

    // ---- P -> LDS in A-operand-friendly layout (swizzled)
#pragma unroll
    for (int j = 0; j < 4; ++j) {
        const int q = w * 16 + g * 4 + j;
#pragma unroll
        for (int n = 0; n < 4; ++n) {
            const int kcol = n * 16 + l16;
            Pl[q * 64 + (kcol ^ ((q & 7) << 3))] = f2bf(p[n][j]);
        }
    }
    __syncthreads();   // Vt (all threads) + Pl ready

    // ---- O = P V
    f32x4 oa[4] = {};
    {
        const int qr = w * 16 + l16;
        bf16x8 a0 = *reinterpret_cast<const bf16x8*>(&Pl[qr * 64 + ((g * 8)      ^ ((qr & 7) << 3))]);
        bf16x8 a1 = *reinterpret_cast<const bf16x8*>(&Pl[qr * 64 + ((32 + g * 8) ^ ((qr & 7) << 3))]);
#pragma unroll
        for (int n = 0; n < 4; ++n) {
            const int vr = n * 16 + l16;
            bf16x8 b0 = *reinterpret_cast<const bf16x8*>(&Vt[vr * 64 + ((g * 8)      ^ ((vr & 7) << 3))]);
            bf16x8 b1 = *reinterpret_cast<const bf16x8*>(&Vt[vr * 64 + ((32 + g * 8) ^ ((vr & 7) << 3))]);
            oa[n] = MFMA16(a0, b0, oa[n]);
            oa[n] = MFMA16(a1, b1, oa[n]);
        }
    }

    // ---- permuted store: Ostd[bb,hh,qq,ll] -> Y[b, s, h*64 + l]
#pragma unroll
    for (int n = 0; n < 4; ++n) {
        const int ll = n * 16 + l16;
#pragma unroll
        for (int r = 0; r < 4; ++r) {
            const int qq = w * 16 + g * 4 + r;
            const int b_ = (bb >> 1) + ((ll >= 32) ? 32 : 0);
            const int s_ = ((bb & 1) << 5) + (qq >> 1);
            const int h_ = ((qq & 1) << 5) + (hh >> 1);
            const int l_ = ((hh & 1) << 5) + (ll & 31);
            Y[(size_t)(b_ * 64 + s_) * 4096 + h_ * 64 + l_] = f2bf(oa[n][r]);
        }
    }
}

// ----------------------------------------------------------------------------
extern "C" void kernel_launch(void* const* d_in, const int* in_sizes, int n_in,
                              void* d_out, int out_size, void* d_ws, size_t ws_size,
                              hipStream_t stream)
{
    (void)in_sizes; (void)n_in; (void)out_size; (void)ws_size;

    const float* x  = (const float*)d_in[0];
    const float* Wq = (const float*)d_in[1];
    const float* bq = (const float*)d_in[2];
    const float* Wk = (const float*)d_in[3];
    const float* bk = (const float*)d_in[4];
    const float* Wv = (const float*)d_in[5];
    const float* bv = (const float*)d_in[6];
    const float* Wp = (const float*)d_in[7];
    const float* bp = (const float*)d_in[8];
    float* out = (float*)d_out;

    const size_t NN = 16777216;            // 4096*4096 elements
    uint16_t* xb   = (uint16_t*)d_ws;      // 32 MB, later reused as Y
    uint16_t* Qb   = xb + NN;              // 32 MB
    uint16_t* Kb   = Qb + NN;              // 32 MB
    uint16_t* Vb   = Kb + NN;              // 32 MB   (total 128 MB)
    uint16_t* Yb   = xb;

    const int n8 = (int)(NN / 8);
    dim3 cgrid((n8 + 255) / 256), cblk(256);
    dim3 ggrid(256), gblk(512);

    cvt_bf16<<<cgrid, cblk, 0, stream>>>(x, xb, n8);

    gemm256<1><<<ggrid, gblk, 0, stream>>>(xb, Wq, bq, (void*)Qb, 4096, 4096, 4096);
    gemm256<1><<<ggrid, gblk, 0, stream>>>(xb, Wk, bk, (void*)Kb, 4096, 4096, 4096);
    gemm256<1><<<ggrid, gblk, 0, stream>>>(xb, Wv, bv, (void*)Vb, 4096, 4096, 4096);

    attn_kernel<<<dim3(4096), dim3(256), 0, stream>>>(Qb, Kb, Vb, Yb);

    gemm256<0><<<ggrid, gblk, 0, stream>>>(Yb, Wp, bp, (void*)out, 4096, 4096, 4096);
}

// Round 8
// 622.880 us; speedup vs baseline: 1.3171x; 1.3171x over previous
//
#include <hip/hip_runtime.h>
#include <stdint.h>

typedef __bf16   bf16x8  __attribute__((ext_vector_type(8)));
typedef float    f32x4   __attribute__((ext_vector_type(4)));
typedef uint16_t u16x8   __attribute__((ext_vector_type(8)));

using as1_cvp = const __attribute__((address_space(1))) void*;
using as3_vp  = __attribute__((address_space(3))) void*;

__device__ __forceinline__ uint16_t f2bf(float f) {
    uint32_t u = __float_as_uint(f);
    u += 0x7FFF + ((u >> 16) & 1);          // RNE
    return (uint16_t)(u >> 16);
}

__device__ __forceinline__ void gload16(const void* g, void* l) {
    __builtin_amdgcn_global_load_lds((as1_cvp)g, (as3_vp)l, 16, 0, 0);
}

#define MFMA16(a, b, c) __builtin_amdgcn_mfma_f32_16x16x32_bf16((a), (b), (c), 0, 0, 0)

// ---------------------------------------------------------------- f32 -> bf16
__global__ __launch_bounds__(256)
void cvt_bf16(const float* __restrict__ in, uint16_t* __restrict__ out, int n8)
{
    int i = blockIdx.x * 256 + threadIdx.x;
    if (i >= n8) return;
    const float4* p = reinterpret_cast<const float4*>(in) + (size_t)i * 2;
    float4 a = p[0], b = p[1];
    u16x8 o;
    o[0] = f2bf(a.x); o[1] = f2bf(a.y); o[2] = f2bf(a.z); o[3] = f2bf(a.w);
    o[4] = f2bf(b.x); o[5] = f2bf(b.y); o[6] = f2bf(b.z); o[7] = f2bf(b.w);
    reinterpret_cast<u16x8*>(out)[i] = o;
}

// ---------------------------------------------------------------------------
// 256x256 GEMM, fully one-phase-ahead fragment pipeline, 4 barriers/tile.
// C = A*Bt^T + bias, both operands bf16 (r7 lesson: f32 B doubles the L2
// panel working set -> panel eviction -> +131MB HBM/dispatch, +85us. Keep B
// bf16 so the 2MB panel stays L2-resident across its 16 consumer blocks).
// 8 waves (2M x 4N), BK=64 as two K-halves of 32; 64B LDS rows, 16B block
// ^= (row>>1)&3 (0 conflicts, r4). All fragment ds_reads issued one phase
// ahead (fly under MFMA via compiler's counted lgkmcnt). Two zero-stall
// vmcnt(6) waits/tile: ph0-end certifies kh1(t) (read at ph1), ph2-end
// certifies kh0(t+1) (read at ph3, across the tile boundary) -- each waits
// only on loads issued >=4 phases earlier. Wait-then-barrier gives global
// (all-wave) certification before any dependent read.
// ---------------------------------------------------------------------------
template <int OUT_BF16>
__global__ __launch_bounds__(512, 2)
void gemm256(const uint16_t* __restrict__ A, const uint16_t* __restrict__ Bt,
             const float* __restrict__ bias, void* __restrict__ Cout,
             int M, int N, int K)
{
    __shared__ uint16_t lds[65536];        // [buf][kh] x (A 256x32 | B 256x32)
    const int NT = K >> 6;                 // K-tiles of 64

    int bid = blockIdx.x;
    bid = (bid & 7) * 32 + (bid >> 3);     // XCD-aware swizzle (nwg=256, %8==0)
    const int bx = bid & 15, by = bid >> 4;
    const int rb = by * 256, cb = bx * 256;

    const int tid  = threadIdx.x;
    const int w    = tid >> 6;
    const int lane = tid & 63;
    const int g    = lane >> 4;
    const int l16  = lane & 15;
    const int wm   = w >> 2;               // 0..1
    const int wn   = w & 3;                // 0..3
    const int srow = lane >> 2;            // stage: 4 lanes per 64B row
    const int sblk = lane & 3;             // stage: 16B block within row

    f32x4 acc[8][4] = {};

    auto stageA = [&](int buf, int kh, int kbase) {
#pragma unroll
        for (int i = 0; i < 2; ++i) {
            const int row = i * 128 + w * 16 + srow;
            const uint16_t* src = A + (size_t)(rb + row) * K + kbase
                                    + ((sblk ^ ((row >> 1) & 3)) << 3);
            gload16(src, &lds[(buf * 2 + kh) * 16384 + i * 4096 + w * 512]);
        }
    };
    auto stageB = [&](int buf, int kh, int kbase) {
#pragma unroll
        for (int i = 0; i < 2; ++i) {
            const int row = i * 128 + w * 16 + srow;
            const uint16_t* src = Bt + (size_t)(cb + row) * K + kbase
                                     + ((sblk ^ ((row >> 1) & 3)) << 3);
            gload16(src, &lds[(buf * 2 + kh) * 16384 + 8192 + i * 4096 + w * 512]);
        }
    };

    auto readA = [&](int base, int grp, bf16x8* dst) {
#pragma unroll
        for (int mi = 0; mi < 4; ++mi) {
            const int r = wm * 128 + grp * 64 + mi * 16 + l16;
            dst[mi] = *reinterpret_cast<const bf16x8*>(
                &lds[base + r * 32 + ((g ^ ((r >> 1) & 3)) << 3)]);
        }
    };
    auto readB = [&](int base, bf16x8* dst) {
#pragma unroll
        for (int n = 0; n < 4; ++n) {
            const int c = wn * 64 + n * 16 + l16;
            dst[n] = *reinterpret_cast<const bf16x8*>(
                &lds[base + 8192 + c * 32 + ((g ^ ((c >> 1) & 3)) << 3)]);
        }
    };

    auto mfma_grp = [&](int grp, const bf16x8* af, const bf16x8* bf) {
        __builtin_amdgcn_s_setprio(1);
#pragma unroll
        for (int mi = 0; mi < 4; ++mi)
#pragma unroll
            for (int n = 0; n < 4; ++n)
                acc[grp * 4 + mi][n] = MFMA16(af[mi], bf[n], acc[grp * 4 + mi][n]);
        __builtin_amdgcn_s_setprio(0);
    };

    // ---- prologue: units A0(0),B0(0),A1(0),B1(0),A0(1),B0(1) = 12 loads.
    // vmcnt(8) completes A0(0),B0(0); barrier -> global; prefetch t0-kh0.
    stageA(0, 0, 0);  stageB(0, 0, 0);
    stageA(0, 1, 32); stageB(0, 1, 32);
    stageA(1, 0, 64); stageB(1, 0, 64);
    asm volatile("s_waitcnt vmcnt(8)" ::: "memory");
    __builtin_amdgcn_s_barrier();

    bf16x8 af0[4], bf0[4];
    readA(0, 0, af0); readB(0, bf0);

    for (int t = 0; t < NT; ++t) {
        const int cur = t & 1, nxt = cur ^ 1;
        const int b0  = (cur * 2 + 0) * 16384;
        const int b1  = (cur * 2 + 1) * 16384;
        const int nb0 = (nxt * 2 + 0) * 16384;
        bf16x8 af1[4], af2[4], af3[4], bf1[4];

        // ---- ph0: stage Ak1(t+1); prefetch af1; MFMA kh0-grp0;
        //      vmcnt certifies kh1(t) for ph1's prefetch.
        if (t + 1 < NT) stageA(nxt, 1, (t + 1) * 64 + 32);
        readA(b0, 1, af1);
        mfma_grp(0, af0, bf0);
        __builtin_amdgcn_sched_barrier(0);
        if (t >= NT - 2) asm volatile("s_waitcnt vmcnt(0)" ::: "memory");
        else             asm volatile("s_waitcnt vmcnt(6)" ::: "memory");
        __builtin_amdgcn_s_barrier();

        // ---- ph1: stage Bk1(t+1); prefetch bf1,af2 (kh1); MFMA kh0-grp1
        if (t + 1 < NT) stageB(nxt, 1, (t + 1) * 64 + 32);
        readB(b1, bf1);
        readA(b1, 0, af2);
        mfma_grp(1, af1, bf0);
        __builtin_amdgcn_sched_barrier(0);
        __builtin_amdgcn_s_barrier();

        // ---- ph2: stage Ak0(t+2); prefetch af3; MFMA kh1-grp0;
        //      vmcnt certifies kh0(t+1) for ph3's cross-boundary prefetch.
        if (t + 2 < NT) stageA(cur, 0, (t + 2) * 64);
        readA(b1, 1, af3);
        mfma_grp(0, af2, bf1);
        __builtin_amdgcn_sched_barrier(0);
        if (t >= NT - 2) asm volatile("s_waitcnt vmcnt(0)" ::: "memory");
        else             asm volatile("s_waitcnt vmcnt(6)" ::: "memory");
        __builtin_amdgcn_s_barrier();

        // ---- ph3: stage Bk0(t+2); prefetch NEXT tile's kh0 frags; MFMA kh1-grp1
        if (t + 2 < NT) stageB(cur, 0, (t + 2) * 64);
        if (t + 1 < NT) { readA(nb0, 0, af0); readB(nb0, bf0); }
        mfma_grp(1, af3, bf1);
        __builtin_amdgcn_sched_barrier(0);
        __builtin_amdgcn_s_barrier();
    }

    // ---- epilogue (16x16 C/D layout: col = l16, row = 4g + r)
    float bv[4];
#pragma unroll
    for (int n = 0; n < 4; ++n) bv[n] = bias[cb + wn * 64 + n * 16 + l16];

#pragma unroll
    for (int m = 0; m < 8; ++m) {
#pragma unroll
        for (int n = 0; n < 4; ++n) {
            const int col = cb + wn * 64 + n * 16 + l16;
#pragma unroll
            for (int r = 0; r < 4; ++r) {
                const int row = rb + wm * 128 + m * 16 + g * 4 + r;
                float v = acc[m][n][r] + bv[n];
                if (OUT_BF16)
                    ((uint16_t*)Cout)[(size_t)row * N + col] = f2bf(v);
                else
                    ((float*)Cout)[(size_t)row * N + col] = v;
            }
        }
    }
}

// ------------------------------------------------------------------ attention
// One block per (bb, hh). 4 waves; wave w owns query rows [16w, 16w+16).
// Unscaled softmax(Q K^T) V, output scattered through the reference's
// cat/transpose/view permutation directly into Y (bf16 [4096 x 4096]).
__global__ __launch_bounds__(256)
void attn_kernel(const uint16_t* __restrict__ Q, const uint16_t* __restrict__ Kg,
                 const uint16_t* __restrict__ V, uint16_t* __restrict__ Y)
{
    const int bid = blockIdx.x;
    const int hh  = bid & 63;
    const int bb  = bid >> 6;
    const int tid = threadIdx.x;
    const int w   = tid >> 6, lane = tid & 63, g = lane >> 4, l16 = lane & 15;

    __shared__ uint16_t Vt[64 * 64];   // V transposed, XOR-swizzled (8 KB)
    __shared__ uint16_t Pl[64 * 64];   // P bf16, XOR-swizzled (8 KB)

    // ---- stage V transposed: Vt[l][k] = V[k][l], swizzle elem k ^= (l&7)<<3
    {
        const int k  = tid >> 2;
        const int l0 = (tid & 3) * 16;
        const uint16_t* src = V + (size_t)(bb * 64 + k) * 4096 + hh * 64 + l0;
        u16x8 v0 = *reinterpret_cast<const u16x8*>(src);
        u16x8 v1 = *reinterpret_cast<const u16x8*>(src + 8);
#pragma unroll
        for (int i = 0; i < 8; ++i) {
            int l = l0 + i;
            Vt[l * 64 + (k ^ ((l & 7) << 3))] = v0[i];
        }
#pragma unroll
        for (int i = 0; i < 8; ++i) {
            int l = l0 + 8 + i;
            Vt[l * 64 + (k ^ ((l & 7) << 3))] = v1[i];
        }
    }

    // ---- S = Q K^T (rows 16w..16w+16, all 64 cols), direct-global fragments
    f32x4 sa[4] = {};
    {
        const uint16_t* qrow = Q + (size_t)(bb * 64 + w * 16 + l16) * 4096 + hh * 64 + g * 8;
        bf16x8 a0 = *reinterpret_cast<const bf16x8*>(qrow);
        bf16x8 a1 = *reinterpret_cast<const bf16x8*>(qrow + 32);
#pragma unroll
        for (int n = 0; n < 4; ++n) {
            const uint16_t* krow = Kg + (size_t)(bb * 64 + n * 16 + l16) * 4096 + hh * 64 + g * 8;
            bf16x8 b0 = *reinterpret_cast<const bf16x8*>(krow);
            bf16x8 b1 = *reinterpret_cast<const bf16x8*>(krow + 32);
            sa[n] = MFMA16(a0, b0, sa[n]);
            sa[n] = MFMA16(a1, b1, sa[n]);
        }
    }

    // ---- softmax (no 1/sqrt(hd) scale, faithful). Row q = 16w + 4g + j;
    // its 64 values live as regs n=0..3 across the 16-lane group (l16).
    float p[4][4];
#pragma unroll
    for (int j = 0; j < 4; ++j) {
        float mx = fmaxf(fmaxf(sa[0][j], sa[1][j]), fmaxf(sa[2][j], sa[3][j]));
        mx = fmaxf(mx, __shfl_xor(mx, 1));
        mx = fmaxf(mx, __shfl_xor(mx, 2));
        mx = fmaxf(mx, __shfl_xor(mx, 4));
        mx = fmaxf(mx, __shfl_xor(mx, 8));
        float s = 0.f;
#pragma unroll
        for (int n = 0; n < 4; ++n) { p[n][j] = __expf(sa[n][j] - mx); s += p[n][j]; }
        s += __shfl_xor(s, 1);
        s += __shfl_xor(s, 2);
        s += __shfl_xor(s, 4);
        s += __shfl_xor(s, 8);
        float inv = 1.0f / s;
#pragma unroll
        for (int n = 0; n < 4; ++n) p[n][j] *= inv;
    }

    // ---- P -> LDS in A-operand-friendly layout (swizzled)
#pragma unroll
    for (int j = 0; j < 4; ++j) {
        const int q = w * 16 + g * 4 + j;
#pragma unroll
        for (int n = 0; n < 4; ++n) {
            const int kcol = n * 16 + l16;
            Pl[q * 64 + (kcol ^ ((q & 7) << 3))] = f2bf(p[n][j]);
        }
    }
    __syncthreads();   // Vt (all threads) + Pl ready

    // ---- O = P V
    f32x4 oa[4] = {};
    {
        const int qr = w * 16 + l16;
        bf16x8 a0 = *reinterpret_cast<const bf16x8*>(&Pl[qr * 64 + ((g * 8)      ^ ((qr & 7) << 3))]);
        bf16x8 a1 = *reinterpret_cast<const bf16x8*>(&Pl[qr * 64 + ((32 + g * 8) ^ ((qr & 7) << 3))]);
#pragma unroll
        for (int n = 0; n < 4; ++n) {
            const int vr = n * 16 + l16;
            bf16x8 b0 = *reinterpret_cast<const bf16x8*>(&Vt[vr * 64 + ((g * 8)      ^ ((vr & 7) << 3))]);
            bf16x8 b1 = *reinterpret_cast<const bf16x8*>(&Vt[vr * 64 + ((32 + g * 8) ^ ((vr & 7) << 3))]);
            oa[n] = MFMA16(a0, b0, oa[n]);
            oa[n] = MFMA16(a1, b1, oa[n]);
        }
    }

    // ---- permuted store: Ostd[bb,hh,qq,ll] -> Y[b, s, h*64 + l]
#pragma unroll
    for (int n = 0; n < 4; ++n) {
        const int ll = n * 16 + l16;
#pragma unroll
        for (int r = 0; r < 4; ++r) {
            const int qq = w * 16 + g * 4 + r;
            const int b_ = (bb >> 1) + ((ll >= 32) ? 32 : 0);
            const int s_ = ((bb & 1) << 5) + (qq >> 1);
            const int h_ = ((qq & 1) << 5) + (hh >> 1);
            const int l_ = ((hh & 1) << 5) + (ll & 31);
            Y[(size_t)(b_ * 64 + s_) * 4096 + h_ * 64 + l_] = f2bf(oa[n][r]);
        }
    }
}

// ----------------------------------------------------------------------------
extern "C" void kernel_launch(void* const* d_in, const int* in_sizes, int n_in,
                              void* d_out, int out_size, void* d_ws, size_t ws_size,
                              hipStream_t stream)
{
    (void)in_sizes; (void)n_in; (void)out_size; (void)ws_size;

    const float* x  = (const float*)d_in[0];
    const float* Wq = (const float*)d_in[1];
    const float* bq = (const float*)d_in[2];
    const float* Wk = (const float*)d_in[3];
    const float* bk = (const float*)d_in[4];
    const float* Wv = (const float*)d_in[5];
    const float* bv = (const float*)d_in[6];
    const float* Wp = (const float*)d_in[7];
    const float* bp = (const float*)d_in[8];
    float* out = (float*)d_out;

    const size_t NN = 16777216;            // 4096*4096 elements
    uint16_t* xb   = (uint16_t*)d_ws;      // 32 MB, later reused as Y
    uint16_t* wb   = xb + NN;              // 32 MB (sequential weight buffer)
    uint16_t* Qb   = wb + NN;              // 32 MB
    uint16_t* Kb   = Qb + NN;              // 32 MB
    uint16_t* Vb   = Kb + NN;              // 32 MB   (total 160 MB)
    uint16_t* Yb   = xb;

    const int n8 = (int)(NN / 8);
    dim3 cgrid((n8 + 255) / 256), cblk(256);
    dim3 ggrid(256), gblk(512);

    cvt_bf16<<<cgrid, cblk, 0, stream>>>(x, xb, n8);

    cvt_bf16<<<cgrid, cblk, 0, stream>>>(Wq, wb, n8);
    gemm256<1><<<ggrid, gblk, 0, stream>>>(xb, wb, bq, (void*)Qb, 4096, 4096, 4096);

    cvt_bf16<<<cgrid, cblk, 0, stream>>>(Wk, wb, n8);
    gemm256<1><<<ggrid, gblk, 0, stream>>>(xb, wb, bk, (void*)Kb, 4096, 4096, 4096);

    cvt_bf16<<<cgrid, cblk, 0, stream>>>(Wv, wb, n8);
    gemm256<1><<<ggrid, gblk, 0, stream>>>(xb, wb, bv, (void*)Vb, 4096, 4096, 4096);

    attn_kernel<<<dim3(4096), dim3(256), 0, stream>>>(Qb, Kb, Vb, Yb);

    cvt_bf16<<<cgrid, cblk, 0, stream>>>(Wp, wb, n8);
    gemm256<0><<<ggrid, gblk, 0, stream>>>(Yb, wb, bp, (void*)out, 4096, 4096, 4096);
}

// Round 9
// 614.548 us; speedup vs baseline: 1.3349x; 1.0136x over previous
//
#include <hip/hip_runtime.h>
#include <stdint.h>

typedef __bf16   bf16x8  __attribute__((ext_vector_type(8)));
typedef float    f32x4   __attribute__((ext_vector_type(4)));
typedef uint16_t u16x8   __attribute__((ext_vector_type(8)));

using as1_cvp = const __attribute__((address_space(1))) void*;
using as3_vp  = __attribute__((address_space(3))) void*;

__device__ __forceinline__ uint16_t f2bf(float f) {
    uint32_t u = __float_as_uint(f);
    u += 0x7FFF + ((u >> 16) & 1);          // RNE
    return (uint16_t)(u >> 16);
}

__device__ __forceinline__ void gload16(const void* g, void* l) {
    __builtin_amdgcn_global_load_lds((as1_cvp)g, (as3_vp)l, 16, 0, 0);
}

#define MFMA16(a, b, c) __builtin_amdgcn_mfma_f32_16x16x32_bf16((a), (b), (c), 0, 0, 0)

// ---------------------------------------------------------------- f32 -> bf16
__global__ __launch_bounds__(256)
void cvt_bf16(const float* __restrict__ in, uint16_t* __restrict__ out, int n8)
{
    int i = blockIdx.x * 256 + threadIdx.x;
    if (i >= n8) return;
    const float4* p = reinterpret_cast<const float4*>(in) + (size_t)i * 2;
    float4 a = p[0], b = p[1];
    u16x8 o;
    o[0] = f2bf(a.x); o[1] = f2bf(a.y); o[2] = f2bf(a.z); o[3] = f2bf(a.w);
    o[4] = f2bf(b.x); o[5] = f2bf(b.y); o[6] = f2bf(b.z); o[7] = f2bf(b.w);
    reinterpret_cast<u16x8*>(out)[i] = o;
}

// ---- merged 5-matrix convert (one launch): regions of 8192 blocks each
__global__ __launch_bounds__(256)
void cvt5(const float* __restrict__ s0, const float* __restrict__ s1,
          const float* __restrict__ s2, const float* __restrict__ s3,
          const float* __restrict__ s4,
          uint16_t* __restrict__ d0, uint16_t* __restrict__ d1,
          uint16_t* __restrict__ d2, uint16_t* __restrict__ d3,
          uint16_t* __restrict__ d4)
{
    const int r = blockIdx.x >> 13;
    const float*  src = (r == 0) ? s0 : (r == 1) ? s1 : (r == 2) ? s2
                       : (r == 3) ? s3 : s4;
    uint16_t*     dst = (r == 0) ? d0 : (r == 1) ? d1 : (r == 2) ? d2
                       : (r == 3) ? d3 : d4;
    const int i = (blockIdx.x & 8191) * 256 + threadIdx.x;
    const float4* p = reinterpret_cast<const float4*>(src) + (size_t)i * 2;
    float4 a = p[0], b = p[1];
    u16x8 o;
    o[0] = f2bf(a.x); o[1] = f2bf(a.y); o[2] = f2bf(a.z); o[3] = f2bf(a.w);
    o[4] = f2bf(b.x); o[5] = f2bf(b.y); o[6] = f2bf(b.z); o[7] = f2bf(b.w);
    reinterpret_cast<u16x8*>(dst)[i] = o;
}

// ---------------------------------------------------------------------------
// 256x256 GEMM, m201-discipline phases: per K-tile 4 phases x {reads+stage ->
// barrier -> lgkmcnt(0)+sched_barrier -> setprio(1) 16 dense MFMA setprio(0)
// -> barrier}. C = A*Bt^T + bias, bf16 operands (r7: f32 B thrashes L2).
// 8 waves (2M x 4N), BK=64 as two K-halves of 32; 64B LDS rows, 16B block
// ^= (row>>1)&3 (0 conflicts, r4). ONE vmcnt(4)/tile at ph_d certifies the
// whole next tile (queue: [Ak0(t+1),Bk0(t+1) from t-1; Ak1(t+1),Bk1(t+1),
// Ak0(t+2),Bk0(t+2) from t] -> wait-to-4 leaves the t+2 pair). Prologue
// vmcnt(4) certifies kh0(0)+kh1(0). Tail t>=NT-2: drain 0. WAR: each stage
// lands >=1 closing-barrier after the last read of its LDS slot.
// Rationale vs r6 (125us, MfmaUtil 50%): keep read region tiny and MFMA
// cluster pure -- r6's interleave smeared addr-VALU into the MFMA cluster,
// stretching phases 1172 vs the template's ~820 cyc (m201: 1563 TF @4k).
// ---------------------------------------------------------------------------
template <int OUT_BF16>
__global__ __launch_bounds__(512, 2)
void gemm256(const uint16_t* __restrict__ A, const uint16_t* __restrict__ Bt,
             const float* __restrict__ bias, void* __restrict__ Cout,
             int M, int N, int K)
{
    __shared__ uint16_t lds[65536];        // [buf][kh] x (A 256x32 | B 256x32)
    const int NT = K >> 6;                 // K-tiles of 64

    int bid = blockIdx.x;
    bid = (bid & 7) * 32 + (bid >> 3);     // XCD-aware swizzle (nwg=256, %8==0)
    const int bx = bid & 15, by = bid >> 4;
    const int rb = by * 256, cb = bx * 256;

    const int tid  = threadIdx.x;
    const int w    = tid >> 6;
    const int lane = tid & 63;
    const int g    = lane >> 4;
    const int l16  = lane & 15;
    const int wm   = w >> 2;               // 0..1
    const int wn   = w & 3;                // 0..3
    const int srow = lane >> 2;            // stage: 4 lanes per 64B row
    const int sblk = lane & 3;             // stage: 16B block within row

    f32x4 acc[8][4] = {};

    auto stageA = [&](int buf, int kh, int kbase) {
#pragma unroll
        for (int i = 0; i < 2; ++i) {
            const int row = i * 128 + w * 16 + srow;
            const uint16_t* src = A + (size_t)(rb + row) * K + kbase
                                    + ((sblk ^ ((row >> 1) & 3)) << 3);
            gload16(src, &lds[(buf * 2 + kh) * 16384 + i * 4096 + w * 512]);
        }
    };
    auto stageB = [&](int buf, int kh, int kbase) {
#pragma unroll
        for (int i = 0; i < 2; ++i) {
            const int row = i * 128 + w * 16 + srow;
            const uint16_t* src = Bt + (size_t)(cb + row) * K + kbase
                                     + ((sblk ^ ((row >> 1) & 3)) << 3);
            gload16(src, &lds[(buf * 2 + kh) * 16384 + 8192 + i * 4096 + w * 512]);
        }
    };

    auto readA = [&](int base, int grp, bf16x8* dst) {
#pragma unroll
        for (int mi = 0; mi < 4; ++mi) {
            const int r = wm * 128 + grp * 64 + mi * 16 + l16;
            dst[mi] = *reinterpret_cast<const bf16x8*>(
                &lds[base + r * 32 + ((g ^ ((r >> 1) & 3)) << 3)]);
        }
    };
    auto readB = [&](int base, bf16x8* dst) {
#pragma unroll
        for (int n = 0; n < 4; ++n) {
            const int c = wn * 64 + n * 16 + l16;
            dst[n] = *reinterpret_cast<const bf16x8*>(
                &lds[base + 8192 + c * 32 + ((g ^ ((c >> 1) & 3)) << 3)]);
        }
    };

    auto mfma_grp = [&](int grp, const bf16x8* af, const bf16x8* bf) {
        __builtin_amdgcn_s_setprio(1);
#pragma unroll
        for (int mi = 0; mi < 4; ++mi)
#pragma unroll
            for (int n = 0; n < 4; ++n)
                acc[grp * 4 + mi][n] = MFMA16(af[mi], bf[n], acc[grp * 4 + mi][n]);
        __builtin_amdgcn_s_setprio(0);
    };

    // ---- prologue: 12 loads; vmcnt(4) certifies kh0(0)+kh1(0)
    stageA(0, 0, 0);  stageB(0, 0, 0);
    stageA(0, 1, 32); stageB(0, 1, 32);
    stageA(1, 0, 64); stageB(1, 0, 64);
    asm volatile("s_waitcnt vmcnt(4)" ::: "memory");
    __builtin_amdgcn_s_barrier();

    for (int t = 0; t < NT; ++t) {
        const int cur = t & 1, nxt = cur ^ 1;
        const int b0 = (cur * 2 + 0) * 16384;
        const int b1 = (cur * 2 + 1) * 16384;
        bf16x8 af[4], bf[4];

        // ---- ph_a: read kh0 grp0 frags; stage Ak1(t+1)
        readA(b0, 0, af); readB(b0, bf);
        if (t + 1 < NT) stageA(nxt, 1, (t + 1) * 64 + 32);
        __builtin_amdgcn_s_barrier();
        asm volatile("s_waitcnt lgkmcnt(0)" ::: "memory");
        __builtin_amdgcn_sched_barrier(0);
        mfma_grp(0, af, bf);
        __builtin_amdgcn_sched_barrier(0);
        __builtin_amdgcn_s_barrier();

        // ---- ph_b: read kh0 grp1 A-frags (B reused in regs); stage Bk1(t+1)
        readA(b0, 1, af);
        if (t + 1 < NT) stageB(nxt, 1, (t + 1) * 64 + 32);
        __builtin_amdgcn_s_barrier();
        asm volatile("s_waitcnt lgkmcnt(0)" ::: "memory");
        __builtin_amdgcn_sched_barrier(0);
        mfma_grp(1, af, bf);
        __builtin_amdgcn_sched_barrier(0);
        __builtin_amdgcn_s_barrier();

        // ---- ph_c: read kh1 grp0 frags; stage Ak0(t+2)
        readA(b1, 0, af); readB(b1, bf);
        if (t + 2 < NT) stageA(cur, 0, (t + 2) * 64);
        __builtin_amdgcn_s_barrier();
        asm volatile("s_waitcnt lgkmcnt(0)" ::: "memory");
        __builtin_amdgcn_sched_barrier(0);
        mfma_grp(0, af, bf);
        __builtin_amdgcn_sched_barrier(0);
        __builtin_amdgcn_s_barrier();

        // ---- ph_d: read kh1 grp1 A-frags; stage Bk0(t+2); tile vmcnt
        readA(b1, 1, af);
        if (t + 2 < NT) stageB(cur, 0, (t + 2) * 64);
        __builtin_amdgcn_s_barrier();
        asm volatile("s_waitcnt lgkmcnt(0)" ::: "memory");
        __builtin_amdgcn_sched_barrier(0);
        mfma_grp(1, af, bf);
        __builtin_amdgcn_sched_barrier(0);
        if (t >= NT - 2) asm volatile("s_waitcnt vmcnt(0)" ::: "memory");
        else             asm volatile("s_waitcnt vmcnt(4)" ::: "memory");
        __builtin_amdgcn_s_barrier();
    }

    // ---- epilogue (16x16 C/D layout: col = l16, row = 4g + r)
    float bv[4];
#pragma unroll
    for (int n = 0; n < 4; ++n) bv[n] = bias[cb + wn * 64 + n * 16 + l16];

#pragma unroll
    for (int m = 0; m < 8; ++m) {
#pragma unroll
        for (int n = 0; n < 4; ++n) {
            const int col = cb + wn * 64 + n * 16 + l16;
#pragma unroll
            for (int r = 0; r < 4; ++r) {
                const int row = rb + wm * 128 + m * 16 + g * 4 + r;
                float v = acc[m][n][r] + bv[n];
                if (OUT_BF16)
                    ((uint16_t*)Cout)[(size_t)row * N + col] = f2bf(v);
                else
                    ((float*)Cout)[(size_t)row * N + col] = v;
            }
        }
    }
}

// ------------------------------------------------------------------ attention
// One block per (bb, hh). 4 waves; wave w owns query rows [16w, 16w+16).
// Unscaled softmax(Q K^T) V, output scattered through the reference's
// cat/transpose/view permutation directly into Y (bf16 [4096 x 4096]).
__global__ __launch_bounds__(256)
void attn_kernel(const uint16_t* __restrict__ Q, const uint16_t* __restrict__ Kg,
                 const uint16_t* __restrict__ V, uint16_t* __restrict__ Y)
{
    const int bid = blockIdx.x;
    const int hh  = bid & 63;
    const int bb  = bid >> 6;
    const int tid = threadIdx.x;
    const int w   = tid >> 6, lane = tid & 63, g = lane >> 4, l16 = lane & 15;

    __shared__ uint16_t Vt[64 * 64];   // V transposed, XOR-swizzled (8 KB)
    __shared__ uint16_t Pl[64 * 64];   // P bf16, XOR-swizzled (8 KB)

    // ---- stage V transposed: Vt[l][k] = V[k][l], swizzle elem k ^= (l&7)<<3
    {
        const int k  = tid >> 2;
        const int l0 = (tid & 3) * 16;
        const uint16_t* src = V + (size_t)(bb * 64 + k) * 4096 + hh * 64 + l0;
        u16x8 v0 = *reinterpret_cast<const u16x8*>(src);
        u16x8 v1 = *reinterpret_cast<const u16x8*>(src + 8);
#pragma unroll
        for (int i = 0; i < 8; ++i) {
            int l = l0 + i;
            Vt[l * 64 + (k ^ ((l & 7) << 3))] = v0[i];
        }
#pragma unroll
        for (int i = 0; i < 8; ++i) {
            int l = l0 + 8 + i;
            Vt[l * 64 + (k ^ ((l & 7) << 3))] = v1[i];
        }
    }

    // ---- S = Q K^T (rows 16w..16w+16, all 64 cols), direct-global fragments
    f32x4 sa[4] = {};
    {
        const uint16_t* qrow = Q + (size_t)(bb * 64 + w * 16 + l16) * 4096 + hh * 64 + g * 8;
        bf16x8 a0 = *reinterpret_cast<const bf16x8*>(qrow);
        bf16x8 a1 = *reinterpret_cast<const bf16x8*>(qrow + 32);
#pragma unroll
        for (int n = 0; n < 4; ++n) {
            const uint16_t* krow = Kg + (size_t)(bb * 64 + n * 16 + l16) * 4096 + hh * 64 + g * 8;
            bf16x8 b0 = *reinterpret_cast<const bf16x8*>(krow);
            bf16x8 b1 = *reinterpret_cast<const bf16x8*>(krow + 32);
            sa[n] = MFMA16(a0, b0, sa[n]);
            sa[n] = MFMA16(a1, b1, sa[n]);
        }
    }

    // ---- softmax (no 1/sqrt(hd) scale, faithful). Row q = 16w + 4g + j;
    // its 64 values live as regs n=0..3 across the 16-lane group (l16).
    float p[4][4];
#pragma unroll
    for (int j = 0; j < 4; ++j) {
        float mx = fmaxf(fmaxf(sa[0][j], sa[1][j]), fmaxf(sa[2][j], sa[3][j]));
        mx = fmaxf(mx, __shfl_xor(mx, 1));
        mx = fmaxf(mx, __shfl_xor(mx, 2));
        mx = fmaxf(mx, __shfl_xor(mx, 4));
        mx = fmaxf(mx, __shfl_xor(mx, 8));
        float s = 0.f;
#pragma unroll
        for (int n = 0; n < 4; ++n) { p[n][j] = __expf(sa[n][j] - mx); s += p[n][j]; }
        s += __shfl_xor(s, 1);
        s += __shfl_xor(s, 2);
        s += __shfl_xor(s, 4);
        s += __shfl_xor(s, 8);
        float inv = 1.0f / s;
#pragma unroll
        for (int n = 0; n < 4; ++n) p[n][j] *= inv;
    }

    // ---- P -> LDS in A-operand-friendly layout (swizzled)
#pragma unroll
    for (int j = 0; j < 4; ++j) {
        const int q = w * 16 + g * 4 + j;
#pragma unroll
        for (int n = 0; n < 4; ++n) {
            const int kcol = n * 16 + l16;
            Pl[q * 64 + (kcol ^ ((q & 7) << 3))] = f2bf(p[n][j]);
        }
    }
    __syncthreads();   // Vt (all threads) + Pl ready

    // ---- O = P V
    f32x4 oa[4] = {};
    {
        const int qr = w * 16 + l16;
        bf16x8 a0 = *reinterpret_cast<const bf16x8*>(&Pl[qr * 64 + ((g * 8)      ^ ((qr & 7) << 3))]);
        bf16x8 a1 = *reinterpret_cast<const bf16x8*>(&Pl[qr * 64 + ((32 + g * 8) ^ ((qr & 7) << 3))]);
#pragma unroll
        for (int n = 0; n < 4; ++n) {
            const int vr = n * 16 + l16;
            bf16x8 b0 = *reinterpret_cast<const bf16x8*>(&Vt[vr * 64 + ((g * 8)      ^ ((vr & 7) << 3))]);
            bf16x8 b1 = *reinterpret_cast<const bf16x8*>(&Vt[vr * 64 + ((32 + g * 8) ^ ((vr & 7) << 3))]);
            oa[n] = MFMA16(a0, b0, oa[n]);
            oa[n] = MFMA16(a1, b1, oa[n]);
        }
    }

    // ---- permuted store: Ostd[bb,hh,qq,ll] -> Y[b, s, h*64 + l]
#pragma unroll
    for (int n = 0; n < 4; ++n) {
        const int ll = n * 16 + l16;
#pragma unroll
        for (int r = 0; r < 4; ++r) {
            const int qq = w * 16 + g * 4 + r;
            const int b_ = (bb >> 1) + ((ll >= 32) ? 32 : 0);
            const int s_ = ((bb & 1) << 5) + (qq >> 1);
            const int h_ = ((qq & 1) << 5) + (hh >> 1);
            const int l_ = ((hh & 1) << 5) + (ll & 31);
            Y[(size_t)(b_ * 64 + s_) * 4096 + h_ * 64 + l_] = f2bf(oa[n][r]);
        }
    }
}

// ----------------------------------------------------------------------------
extern "C" void kernel_launch(void* const* d_in, const int* in_sizes, int n_in,
                              void* d_out, int out_size, void* d_ws, size_t ws_size,
                              hipStream_t stream)
{
    (void)in_sizes; (void)n_in; (void)out_size;

    const float* x  = (const float*)d_in[0];
    const float* Wq = (const float*)d_in[1];
    const float* bq = (const float*)d_in[2];
    const float* Wk = (const float*)d_in[3];
    const float* bk = (const float*)d_in[4];
    const float* Wv = (const float*)d_in[5];
    const float* bv = (const float*)d_in[6];
    const float* Wp = (const float*)d_in[7];
    const float* bp = (const float*)d_in[8];
    float* out = (float*)d_out;

    const size_t NN = 16777216;            // 4096*4096 elements
    const int n8 = (int)(NN / 8);
    dim3 cgrid((n8 + 255) / 256), cblk(256);
    dim3 ggrid(256), gblk(512);

    if (ws_size >= NN * 2 * 8) {
        // merged-cvt path: all 5 converts in one launch (needs 256 MB ws)
        uint16_t* xb  = (uint16_t*)d_ws;   // later reused as Y
        uint16_t* wqb = xb  + NN;
        uint16_t* wkb = wqb + NN;
        uint16_t* wvb = wkb + NN;
        uint16_t* wpb = wvb + NN;
        uint16_t* Qb  = wpb + NN;
        uint16_t* Kb  = Qb  + NN;
        uint16_t* Vb  = Kb  + NN;
        uint16_t* Yb  = xb;

        cvt5<<<dim3(8192 * 5), cblk, 0, stream>>>(x, Wq, Wk, Wv, Wp,
                                                  xb, wqb, wkb, wvb, wpb);
        gemm256<1><<<ggrid, gblk, 0, stream>>>(xb, wqb, bq, (void*)Qb, 4096, 4096, 4096);
        gemm256<1><<<ggrid, gblk, 0, stream>>>(xb, wkb, bk, (void*)Kb, 4096, 4096, 4096);
        gemm256<1><<<ggrid, gblk, 0, stream>>>(xb, wvb, bv, (void*)Vb, 4096, 4096, 4096);
        attn_kernel<<<dim3(4096), dim3(256), 0, stream>>>(Qb, Kb, Vb, Yb);
        gemm256<0><<<ggrid, gblk, 0, stream>>>(Yb, wpb, bp, (void*)out, 4096, 4096, 4096);
    } else {
        // sequential-wb fallback (160 MB ws)
        uint16_t* xb = (uint16_t*)d_ws;
        uint16_t* wb = xb + NN;
        uint16_t* Qb = wb + NN;
        uint16_t* Kb = Qb + NN;
        uint16_t* Vb = Kb + NN;
        uint16_t* Yb = xb;

        cvt_bf16<<<cgrid, cblk, 0, stream>>>(x, xb, n8);
        cvt_bf16<<<cgrid, cblk, 0, stream>>>(Wq, wb, n8);
        gemm256<1><<<ggrid, gblk, 0, stream>>>(xb, wb, bq, (void*)Qb, 4096, 4096, 4096);
        cvt_bf16<<<cgrid, cblk, 0, stream>>>(Wk, wb, n8);
        gemm256<1><<<ggrid, gblk, 0, stream>>>(xb, wb, bk, (void*)Kb, 4096, 4096, 4096);
        cvt_bf16<<<cgrid, cblk, 0, stream>>>(Wv, wb, n8);
        gemm256<1><<<ggrid, gblk, 0, stream>>>(xb, wb, bv, (void*)Vb, 4096, 4096, 4096);
        attn_kernel<<<dim3(4096), dim3(256), 0, stream>>>(Qb, Kb, Vb, Yb);
        cvt_bf16<<<cgrid, cblk, 0, stream>>>(Wp, wb, n8);
        gemm256<0><<<ggrid, gblk, 0, stream>>>(Yb, wb, bp, (void*)out, 4096, 4096, 4096);
    }
}

// Round 10
// 599.885 us; speedup vs baseline: 1.3676x; 1.0244x over previous
//
#include <hip/hip_runtime.h>
#include <stdint.h>

typedef __bf16   bf16x8  __attribute__((ext_vector_type(8)));
typedef float    f32x4   __attribute__((ext_vector_type(4)));
typedef uint16_t u16x8   __attribute__((ext_vector_type(8)));

using as1_cvp = const __attribute__((address_space(1))) void*;
using as3_vp  = __attribute__((address_space(3))) void*;

__device__ __forceinline__ uint16_t f2bf(float f) {
    uint32_t u = __float_as_uint(f);
    u += 0x7FFF + ((u >> 16) & 1);          // RNE
    return (uint16_t)(u >> 16);
}

__device__ __forceinline__ void gload16(const void* g, void* l) {
    __builtin_amdgcn_global_load_lds((as1_cvp)g, (as3_vp)l, 16, 0, 0);
}

#define MFMA16(a, b, c) __builtin_amdgcn_mfma_f32_16x16x32_bf16((a), (b), (c), 0, 0, 0)

// ---------------------------------------------------------------- f32 -> bf16
__global__ __launch_bounds__(256)
void cvt_bf16(const float* __restrict__ in, uint16_t* __restrict__ out, int n8)
{
    int i = blockIdx.x * 256 + threadIdx.x;
    if (i >= n8) return;
    const float4* p = reinterpret_cast<const float4*>(in) + (size_t)i * 2;
    float4 a = p[0], b = p[1];
    u16x8 o;
    o[0] = f2bf(a.x); o[1] = f2bf(a.y); o[2] = f2bf(a.z); o[3] = f2bf(a.w);
    o[4] = f2bf(b.x); o[5] = f2bf(b.y); o[6] = f2bf(b.z); o[7] = f2bf(b.w);
    reinterpret_cast<u16x8*>(out)[i] = o;
}

// ---- merged 5-matrix convert (one launch, saves ~34us of launch overhead)
__global__ __launch_bounds__(256)
void cvt5(const float* __restrict__ s0, const float* __restrict__ s1,
          const float* __restrict__ s2, const float* __restrict__ s3,
          const float* __restrict__ s4,
          uint16_t* __restrict__ d0, uint16_t* __restrict__ d1,
          uint16_t* __restrict__ d2, uint16_t* __restrict__ d3,
          uint16_t* __restrict__ d4)
{
    const int r = blockIdx.x >> 13;
    const float*  src = (r == 0) ? s0 : (r == 1) ? s1 : (r == 2) ? s2
                       : (r == 3) ? s3 : s4;
    uint16_t*     dst = (r == 0) ? d0 : (r == 1) ? d1 : (r == 2) ? d2
                       : (r == 3) ? d3 : d4;
    const int i = (blockIdx.x & 8191) * 256 + threadIdx.x;
    const float4* p = reinterpret_cast<const float4*>(src) + (size_t)i * 2;
    float4 a = p[0], b = p[1];
    u16x8 o;
    o[0] = f2bf(a.x); o[1] = f2bf(a.y); o[2] = f2bf(a.z); o[3] = f2bf(a.w);
    o[4] = f2bf(b.x); o[5] = f2bf(b.y); o[6] = f2bf(b.z); o[7] = f2bf(b.w);
    reinterpret_cast<u16x8*>(dst)[i] = o;
}

// ---------------------------------------------------------------------------
// 256x256 GEMM — r6 structure (measured best: 125us, MfmaUtil 50%, 0 bank
// conflicts). C = A*Bt^T + bias, bf16 operands (r7: f32 B thrashes L2).
// 8 waves (2M x 4N), BK=64 as two K-halves of 32; 64B LDS rows, 16B block
// ^= (row>>1)&3. Pipelined fragments: each phase {stage-issue; ds_reads for
// NEXT phase's frags; MFMA on frags read LAST phase}; raw s_barrier does
// not drain lgkm -> compiler's counted lgkmcnt lets prefetch reads fly
// under the current MFMA cluster (this interleave BEATS lockstep-drain
// phases: r4 139.7/42%, r9 137.3/44.7% vs r6 125.1/50% — with 2 waves/SIMD
// the drained phase exposes the read burst serially).
// ONE vmcnt(4)/tile at ph3: queue at that point = [kh0(t+1) 4 loads from
// t-1, kh1(t+1) 4 from t, kh0(t+2) 4 from t]; wait-to-4 completes ALL of
// tile t+1. ph0's in-phase reads are thus certified by the ph3 barrier.
// Tail t>=NT-2: drain 0. WAR: each stage lands >=1 closing-barrier after
// the last read of its LDS slot.
// ---------------------------------------------------------------------------
template <int OUT_BF16>
__global__ __launch_bounds__(512, 2)
void gemm256(const uint16_t* __restrict__ A, const uint16_t* __restrict__ Bt,
             const float* __restrict__ bias, void* __restrict__ Cout,
             int M, int N, int K)
{
    __shared__ uint16_t lds[65536];        // [buf][kh] x (A 256x32 | B 256x32)
    const int NT = K >> 6;                 // K-tiles of 64

    int bid = blockIdx.x;
    bid = (bid & 7) * 32 + (bid >> 3);     // XCD-aware swizzle (nwg=256, %8==0)
    const int bx = bid & 15, by = bid >> 4;
    const int rb = by * 256, cb = bx * 256;

    const int tid  = threadIdx.x;
    const int w    = tid >> 6;
    const int lane = tid & 63;
    const int g    = lane >> 4;
    const int l16  = lane & 15;
    const int wm   = w >> 2;               // 0..1
    const int wn   = w & 3;                // 0..3
    const int srow = lane >> 2;            // stage: 4 lanes per 64B row
    const int sblk = lane & 3;             // stage: 16B block within row

    f32x4 acc[8][4] = {};

    auto stageA = [&](int buf, int kh, int kbase) {
#pragma unroll
        for (int i = 0; i < 2; ++i) {
            const int row = i * 128 + w * 16 + srow;
            const uint16_t* src = A + (size_t)(rb + row) * K + kbase
                                    + ((sblk ^ ((row >> 1) & 3)) << 3);
            gload16(src, &lds[(buf * 2 + kh) * 16384 + i * 4096 + w * 512]);
        }
    };
    auto stageB = [&](int buf, int kh, int kbase) {
#pragma unroll
        for (int i = 0; i < 2; ++i) {
            const int row = i * 128 + w * 16 + srow;
            const uint16_t* src = Bt + (size_t)(cb + row) * K + kbase
                                     + ((sblk ^ ((row >> 1) & 3)) << 3);
            gload16(src, &lds[(buf * 2 + kh) * 16384 + 8192 + i * 4096 + w * 512]);
        }
    };

    auto readA = [&](int base, int grp, bf16x8* dst) {
#pragma unroll
        for (int mi = 0; mi < 4; ++mi) {
            const int r = wm * 128 + grp * 64 + mi * 16 + l16;
            dst[mi] = *reinterpret_cast<const bf16x8*>(
                &lds[base + r * 32 + ((g ^ ((r >> 1) & 3)) << 3)]);
        }
    };
    auto readB = [&](int base, bf16x8* dst) {
#pragma unroll
        for (int n = 0; n < 4; ++n) {
            const int c = wn * 64 + n * 16 + l16;
            dst[n] = *reinterpret_cast<const bf16x8*>(
                &lds[base + 8192 + c * 32 + ((g ^ ((c >> 1) & 3)) << 3)]);
        }
    };

    auto mfma_grp = [&](int grp, const bf16x8* af, const bf16x8* bf) {
        __builtin_amdgcn_s_setprio(1);
#pragma unroll
        for (int mi = 0; mi < 4; ++mi)
#pragma unroll
            for (int n = 0; n < 4; ++n)
                acc[grp * 4 + mi][n] = MFMA16(af[mi], bf[n], acc[grp * 4 + mi][n]);
        __builtin_amdgcn_s_setprio(0);
    };

    // ---- prologue: t0 kh0, t0 kh1, t1 kh0 (12 loads; vmcnt(4) -> t0 landed)
    stageA(0, 0, 0);  stageB(0, 0, 0);
    stageA(0, 1, 32); stageB(0, 1, 32);
    stageA(1, 0, 64); stageB(1, 0, 64);
    asm volatile("s_waitcnt vmcnt(4)" ::: "memory");
    __builtin_amdgcn_s_barrier();

    for (int t = 0; t < NT; ++t) {
        const int cur = t & 1, nxt = cur ^ 1;
        const int b0 = (cur * 2 + 0) * 16384;
        const int b1 = (cur * 2 + 1) * 16384;
        bf16x8 af0[4], af1[4], af2[4], af3[4], bf0[4], bf1[4];

        // ---- ph0: stage Ak1(t+1); read af0,bf0 (certified by ph3(t-1));
        //      prefetch af1; MFMA kh0-grp0
        if (t + 1 < NT) stageA(nxt, 1, (t + 1) * 64 + 32);
        readA(b0, 0, af0); readB(b0, bf0);
        readA(b0, 1, af1);                 // counted-lgkm: flies under MFMA
        mfma_grp(0, af0, bf0);
        __builtin_amdgcn_sched_barrier(0);
        __builtin_amdgcn_s_barrier();

        // ---- ph1: stage Bk1(t+1); prefetch bf1,af2 (kh1); MFMA kh0-grp1
        if (t + 1 < NT) stageB(nxt, 1, (t + 1) * 64 + 32);
        readB(b1, bf1);
        readA(b1, 0, af2);
        mfma_grp(1, af1, bf0);
        __builtin_amdgcn_sched_barrier(0);
        __builtin_amdgcn_s_barrier();

        // ---- ph2: stage Ak0(t+2); prefetch af3; MFMA kh1-grp0
        if (t + 2 < NT) stageA(cur, 0, (t + 2) * 64);
        readA(b1, 1, af3);
        mfma_grp(0, af2, bf1);
        __builtin_amdgcn_sched_barrier(0);
        __builtin_amdgcn_s_barrier();

        // ---- ph3: stage Bk0(t+2); MFMA kh1-grp1; tile-boundary vmcnt
        if (t + 2 < NT) stageB(cur, 0, (t + 2) * 64);
        mfma_grp(1, af3, bf1);
        __builtin_amdgcn_sched_barrier(0);
        if (t >= NT - 2) asm volatile("s_waitcnt vmcnt(0)" ::: "memory");
        else             asm volatile("s_waitcnt vmcnt(4)" ::: "memory");
        __builtin_amdgcn_s_barrier();
    }

    // ---- epilogue (16x16 C/D layout: col = l16, row = 4g + r)
    float bv[4];
#pragma unroll
    for (int n = 0; n < 4; ++n) bv[n] = bias[cb + wn * 64 + n * 16 + l16];

#pragma unroll
    for (int m = 0; m < 8; ++m) {
#pragma unroll
        for (int n = 0; n < 4; ++n) {
            const int col = cb + wn * 64 + n * 16 + l16;
#pragma unroll
            for (int r = 0; r < 4; ++r) {
                const int row = rb + wm * 128 + m * 16 + g * 4 + r;
                float v = acc[m][n][r] + bv[n];
                if (OUT_BF16)
                    ((uint16_t*)Cout)[(size_t)row * N + col] = f2bf(v);
                else
                    ((float*)Cout)[(size_t)row * N + col] = v;
            }
        }
    }
}

// ------------------------------------------------------------------ attention
// One block per (bb, hh). 4 waves; wave w owns query rows [16w, 16w+16).
// Unscaled softmax(Q K^T) V, output scattered through the reference's
// cat/transpose/view permutation directly into Y (bf16 [4096 x 4096]).
__global__ __launch_bounds__(256)
void attn_kernel(const uint16_t* __restrict__ Q, const uint16_t* __restrict__ Kg,
                 const uint16_t* __restrict__ V, uint16_t* __restrict__ Y)
{
    const int bid = blockIdx.x;
    const int hh  = bid & 63;
    const int bb  = bid >> 6;
    const int tid = threadIdx.x;
    const int w   = tid >> 6, lane = tid & 63, g = lane >> 4, l16 = lane & 15;

    __shared__ uint16_t Vt[64 * 64];   // V transposed, XOR-swizzled (8 KB)
    __shared__ uint16_t Pl[64 * 64];   // P bf16, XOR-swizzled (8 KB)

    // ---- stage V transposed: Vt[l][k] = V[k][l], swizzle elem k ^= (l&7)<<3
    {
        const int k  = tid >> 2;
        const int l0 = (tid & 3) * 16;
        const uint16_t* src = V + (size_t)(bb * 64 + k) * 4096 + hh * 64 + l0;
        u16x8 v0 = *reinterpret_cast<const u16x8*>(src);
        u16x8 v1 = *reinterpret_cast<const u16x8*>(src + 8);
#pragma unroll
        for (int i = 0; i < 8; ++i) {
            int l = l0 + i;
            Vt[l * 64 + (k ^ ((l & 7) << 3))] = v0[i];
        }
#pragma unroll
        for (int i = 0; i < 8; ++i) {
            int l = l0 + 8 + i;
            Vt[l * 64 + (k ^ ((l & 7) << 3))] = v1[i];
        }
    }

    // ---- S = Q K^T (rows 16w..16w+16, all 64 cols), direct-global fragments
    f32x4 sa[4] = {};
    {
        const uint16_t* qrow = Q + (size_t)(bb * 64 + w * 16 + l16) * 4096 + hh * 64 + g * 8;
        bf16x8 a0 = *reinterpret_cast<const bf16x8*>(qrow);
        bf16x8 a1 = *reinterpret_cast<const bf16x8*>(qrow + 32);
#pragma unroll
        for (int n = 0; n < 4; ++n) {
            const uint16_t* krow = Kg + (size_t)(bb * 64 + n * 16 + l16) * 4096 + hh * 64 + g * 8;
            bf16x8 b0 = *reinterpret_cast<const bf16x8*>(krow);
            bf16x8 b1 = *reinterpret_cast<const bf16x8*>(krow + 32);
            sa[n] = MFMA16(a0, b0, sa[n]);
            sa[n] = MFMA16(a1, b1, sa[n]);
        }
    }

    // ---- softmax (no 1/sqrt(hd) scale, faithful). Row q = 16w + 4g + j;
    // its 64 values live as regs n=0..3 across the 16-lane group (l16).
    float p[4][4];
#pragma unroll
    for (int j = 0; j < 4; ++j) {
        float mx = fmaxf(fmaxf(sa[0][j], sa[1][j]), fmaxf(sa[2][j], sa[3][j]));
        mx = fmaxf(mx, __shfl_xor(mx, 1));
        mx = fmaxf(mx, __shfl_xor(mx, 2));
        mx = fmaxf(mx, __shfl_xor(mx, 4));
        mx = fmaxf(mx, __shfl_xor(mx, 8));
        float s = 0.f;
#pragma unroll
        for (int n = 0; n < 4; ++n) { p[n][j] = __expf(sa[n][j] - mx); s += p[n][j]; }
        s += __shfl_xor(s, 1);
        s += __shfl_xor(s, 2);
        s += __shfl_xor(s, 4);
        s += __shfl_xor(s, 8);
        float inv = 1.0f / s;
#pragma unroll
        for (int n = 0; n < 4; ++n) p[n][j] *= inv;
    }

    // ---- P -> LDS in A-operand-friendly layout (swizzled)
#pragma unroll
    for (int j = 0; j < 4; ++j) {
        const int q = w * 16 + g * 4 + j;
#pragma unroll
        for (int n = 0; n < 4; ++n) {
            const int kcol = n * 16 + l16;
            Pl[q * 64 + (kcol ^ ((q & 7) << 3))] = f2bf(p[n][j]);
        }
    }
    __syncthreads();   // Vt (all threads) + Pl ready

    // ---- O = P V
    f32x4 oa[4] = {};
    {
        const int qr = w * 16 + l16;
        bf16x8 a0 = *reinterpret_cast<const bf16x8*>(&Pl[qr * 64 + ((g * 8)      ^ ((qr & 7) << 3))]);
        bf16x8 a1 = *reinterpret_cast<const bf16x8*>(&Pl[qr * 64 + ((32 + g * 8) ^ ((qr & 7) << 3))]);
#pragma unroll
        for (int n = 0; n < 4; ++n) {
            const int vr = n * 16 + l16;
            bf16x8 b0 = *reinterpret_cast<const bf16x8*>(&Vt[vr * 64 + ((g * 8)      ^ ((vr & 7) << 3))]);
            bf16x8 b1 = *reinterpret_cast<const bf16x8*>(&Vt[vr * 64 + ((32 + g * 8) ^ ((vr & 7) << 3))]);
            oa[n] = MFMA16(a0, b0, oa[n]);
            oa[n] = MFMA16(a1, b1, oa[n]);
        }
    }

    // ---- permuted store: Ostd[bb,hh,qq,ll] -> Y[b, s, h*64 + l]
#pragma unroll
    for (int n = 0; n < 4; ++n) {
        const int ll = n * 16 + l16;
#pragma unroll
        for (int r = 0; r < 4; ++r) {
            const int qq = w * 16 + g * 4 + r;
            const int b_ = (bb >> 1) + ((ll >= 32) ? 32 : 0);
            const int s_ = ((bb & 1) << 5) + (qq >> 1);
            const int h_ = ((qq & 1) << 5) + (hh >> 1);
            const int l_ = ((hh & 1) << 5) + (ll & 31);
            Y[(size_t)(b_ * 64 + s_) * 4096 + h_ * 64 + l_] = f2bf(oa[n][r]);
        }
    }
}

// ----------------------------------------------------------------------------
extern "C" void kernel_launch(void* const* d_in, const int* in_sizes, int n_in,
                              void* d_out, int out_size, void* d_ws, size_t ws_size,
                              hipStream_t stream)
{
    (void)in_sizes; (void)n_in; (void)out_size;

    const float* x  = (const float*)d_in[0];
    const float* Wq = (const float*)d_in[1];
    const float* bq = (const float*)d_in[2];
    const float* Wk = (const float*)d_in[3];
    const float* bk = (const float*)d_in[4];
    const float* Wv = (const float*)d_in[5];
    const float* bv = (const float*)d_in[6];
    const float* Wp = (const float*)d_in[7];
    const float* bp = (const float*)d_in[8];
    float* out = (float*)d_out;

    const size_t NN = 16777216;            // 4096*4096 elements
    const int n8 = (int)(NN / 8);
    dim3 cgrid((n8 + 255) / 256), cblk(256);
    dim3 ggrid(256), gblk(512);

    if (ws_size >= NN * 2 * 8) {
        // merged-cvt path: all 5 converts in one launch (needs 256 MB ws)
        uint16_t* xb  = (uint16_t*)d_ws;   // later reused as Y
        uint16_t* wqb = xb  + NN;
        uint16_t* wkb = wqb + NN;
        uint16_t* wvb = wkb + NN;
        uint16_t* wpb = wvb + NN;
        uint16_t* Qb  = wpb + NN;
        uint16_t* Kb  = Qb  + NN;
        uint16_t* Vb  = Kb  + NN;
        uint16_t* Yb  = xb;

        cvt5<<<dim3(8192 * 5), cblk, 0, stream>>>(x, Wq, Wk, Wv, Wp,
                                                  xb, wqb, wkb, wvb, wpb);
        gemm256<1><<<ggrid, gblk, 0, stream>>>(xb, wqb, bq, (void*)Qb, 4096, 4096, 4096);
        gemm256<1><<<ggrid, gblk, 0, stream>>>(xb, wkb, bk, (void*)Kb, 4096, 4096, 4096);
        gemm256<1><<<ggrid, gblk, 0, stream>>>(xb, wvb, bv, (void*)Vb, 4096, 4096, 4096);
        attn_kernel<<<dim3(4096), dim3(256), 0, stream>>>(Qb, Kb, Vb, Yb);
        gemm256<0><<<ggrid, gblk, 0, stream>>>(Yb, wpb, bp, (void*)out, 4096, 4096, 4096);
    } else {
        // sequential-wb fallback (160 MB ws)
        uint16_t* xb = (uint16_t*)d_ws;
        uint16_t* wb = xb + NN;
        uint16_t* Qb = wb + NN;
        uint16_t* Kb = Qb + NN;
        uint16_t* Vb = Kb + NN;
        uint16_t* Yb = xb;

        cvt_bf16<<<cgrid, cblk, 0, stream>>>(x, xb, n8);
        cvt_bf16<<<cgrid, cblk, 0, stream>>>(Wq, wb, n8);
        gemm256<1><<<ggrid, gblk, 0, stream>>>(xb, wb, bq, (void*)Qb, 4096, 4096, 4096);
        cvt_bf16<<<cgrid, cblk, 0, stream>>>(Wk, wb, n8);
        gemm256<1><<<ggrid, gblk, 0, stream>>>(xb, wb, bk, (void*)Kb, 4096, 4096, 4096);
        cvt_bf16<<<cgrid, cblk, 0, stream>>>(Wv, wb, n8);
        gemm256<1><<<ggrid, gblk, 0, stream>>>(xb, wb, bv, (void*)Vb, 4096, 4096, 4096);
        attn_kernel<<<dim3(4096), dim3(256), 0, stream>>>(Qb, Kb, Vb, Yb);
        cvt_bf16<<<cgrid, cblk, 0, stream>>>(Wp, wb, n8);
        gemm256<0><<<ggrid, gblk, 0, stream>>>(Yb, wb, bp, (void*)out, 4096, 4096, 4096);
    }
}